// Round 1
// baseline (5542.807 us; speedup 1.0000x reference)
//
#include <hip/hip_runtime.h>
#include <hip/hip_bf16.h>
#include <math.h>

#define EPSF 1e-5f

// ---------------- conv1 + bn1 + relu + pool1 ----------------
// x (64,3,480,480) -> y1 (64,16,60,60)
__global__ __launch_bounds__(256) void k_conv1(
    const float* __restrict__ x, const float* __restrict__ w1,
    const float* __restrict__ b1, const float* __restrict__ g1,
    const float* __restrict__ be1, const float* __restrict__ m1,
    const float* __restrict__ v1, float* __restrict__ y1)
{
    __shared__ float wl[768];          // [c][kr][kc][ch]
    __shared__ float al[16], dl[16];
    int tid = threadIdx.x;
    for (int s = tid; s < 768; s += 256) {
        int ch = s / 48; int rem = s - ch * 48;   // rem = c*16 + kr*4 + kc
        wl[rem * 16 + ch] = w1[s];
    }
    if (tid < 16) {
        float a = g1[tid] / sqrtf(v1[tid] + EPSF);
        al[tid] = a;
        dl[tid] = be1[tid] + a * (b1[tid] - m1[tid]);
    }
    __syncthreads();

    int b = blockIdx.y;
    int pix = blockIdx.x * 256 + tid;
    if (pix >= 3600) return;
    int ph = pix / 60, pw = pix - ph * 60;

    float acc[4][16];
#pragma unroll
    for (int i = 0; i < 4; ++i)
#pragma unroll
        for (int ch = 0; ch < 16; ++ch) acc[i][ch] = 0.f;

    const float* xb = x + (size_t)b * 3 * 480 * 480;
#pragma unroll
    for (int c = 0; c < 3; ++c) {
        const float* xc = xb + (size_t)c * 480 * 480;
#pragma unroll
        for (int kr = 0; kr < 4; ++kr) {
            const float* r0 = xc + (size_t)(ph * 8 + kr) * 480 + pw * 8;
            const float* r1 = r0 + 4 * 480;
            float4 A0 = *(const float4*)r0;
            float4 A1 = *(const float4*)(r0 + 4);
            float4 B0 = *(const float4*)r1;
            float4 B1 = *(const float4*)(r1 + 4);
            const float* wbase = &wl[(c * 4 + kr) * 64];
#pragma unroll
            for (int kc = 0; kc < 4; ++kc) {
                float p00 = ((const float*)&A0)[kc];
                float p01 = ((const float*)&A1)[kc];
                float p10 = ((const float*)&B0)[kc];
                float p11 = ((const float*)&B1)[kc];
                const float4* wv4 = (const float4*)(wbase + kc * 16);
#pragma unroll
                for (int q = 0; q < 4; ++q) {
                    float4 w = wv4[q];
                    acc[0][q*4+0] += p00 * w.x; acc[0][q*4+1] += p00 * w.y;
                    acc[0][q*4+2] += p00 * w.z; acc[0][q*4+3] += p00 * w.w;
                    acc[1][q*4+0] += p01 * w.x; acc[1][q*4+1] += p01 * w.y;
                    acc[1][q*4+2] += p01 * w.z; acc[1][q*4+3] += p01 * w.w;
                    acc[2][q*4+0] += p10 * w.x; acc[2][q*4+1] += p10 * w.y;
                    acc[2][q*4+2] += p10 * w.z; acc[2][q*4+3] += p10 * w.w;
                    acc[3][q*4+0] += p11 * w.x; acc[3][q*4+1] += p11 * w.y;
                    acc[3][q*4+2] += p11 * w.z; acc[3][q*4+3] += p11 * w.w;
                }
            }
        }
    }

    float* yb = y1 + (size_t)b * 16 * 3600 + ph * 60 + pw;
#pragma unroll
    for (int ch = 0; ch < 16; ++ch) {
        float a = al[ch], d = dl[ch];
        float v0 = fmaxf(a * acc[0][ch] + d, 0.f);
        float v1x = fmaxf(a * acc[1][ch] + d, 0.f);
        float v2x = fmaxf(a * acc[2][ch] + d, 0.f);
        float v3x = fmaxf(a * acc[3][ch] + d, 0.f);
        yb[(size_t)ch * 3600] = fmaxf(fmaxf(v0, v1x), fmaxf(v2x, v3x));
    }
}

// ---------------- conv2 + bn2 + relu + pool2 ----------------
// y1 (64,16,60,60) -> cbuf (64,100)
__global__ __launch_bounds__(256) void k_conv2(
    const float* __restrict__ y1, const float* __restrict__ w2,
    const float* __restrict__ b2, const float* __restrict__ g2,
    const float* __restrict__ be2, const float* __restrict__ m2,
    const float* __restrict__ v2q, float* __restrict__ cbuf)
{
    __shared__ float wl[144];
    __shared__ float a2s, d2s;
    int tid = threadIdx.x;
    if (tid < 144) wl[tid] = w2[tid];
    if (tid == 0) {
        float a = g2[0] / sqrtf(v2q[0] + EPSF);
        a2s = a;
        d2s = be2[0] + a * (b2[0] - m2[0]);
    }
    __syncthreads();
    int idx = blockIdx.x * 256 + tid;
    if (idx >= 6400) return;
    int b = idx / 100; int i = idx - b * 100;
    int ph = i / 10, pw = i - ph * 10;

    float acc[4] = {0.f, 0.f, 0.f, 0.f};
    const float* yb = y1 + (size_t)b * 16 * 3600;
    for (int c = 0; c < 16; ++c) {
        const float* yc = yb + (size_t)c * 3600;
#pragma unroll
        for (int pr = 0; pr < 2; ++pr)
#pragma unroll
            for (int kr = 0; kr < 3; ++kr) {
                const float* row = yc + (ph * 6 + pr * 3 + kr) * 60 + pw * 6;
                float x0 = row[0], x1 = row[1], x2 = row[2];
                float x3 = row[3], x4 = row[4], x5 = row[5];
                const float* wr = &wl[(c * 3 + kr) * 3];
                float w0 = wr[0], w1v = wr[1], w2v = wr[2];
                acc[pr*2+0] += x0 * w0 + x1 * w1v + x2 * w2v;
                acc[pr*2+1] += x3 * w0 + x4 * w1v + x5 * w2v;
            }
    }
    float a = a2s, d = d2s;
    float q0 = fmaxf(a * acc[0] + d, 0.f);
    float q1 = fmaxf(a * acc[1] + d, 0.f);
    float q2 = fmaxf(a * acc[2] + d, 0.f);
    float q3 = fmaxf(a * acc[3] + d, 0.f);
    cbuf[idx] = fmaxf(fmaxf(q0, q1), fmaxf(q2, q3));
}

// ---------------- MLP + argmax -> pre ----------------
__global__ __launch_bounds__(256) void k_mlp(
    const float* __restrict__ cbuf,
    const float* __restrict__ w1, const float* __restrict__ b1,
    const float* __restrict__ w2, const float* __restrict__ b2,
    const float* __restrict__ w3, const float* __restrict__ b3,
    int* __restrict__ pre)
{
    __shared__ float cl[64 * 101];
    __shared__ float h1[64 * 33];
    __shared__ float h2[64 * 33];
    int tid = threadIdx.x;
    for (int s = tid; s < 6400; s += 256) {
        int bb = s / 100, k = s - bb * 100;
        cl[bb * 101 + k] = cbuf[s];
    }
    __syncthreads();
    int b = tid & 63, q = tid >> 6;     // wave-uniform q
#pragma unroll
    for (int jj = 0; jj < 8; ++jj) {
        int j = q * 8 + jj;
        float s = b1[j];
        const float* wr = w1 + j * 100;
        const float* cr = &cl[b * 101];
        for (int k = 0; k < 100; ++k) s += cr[k] * wr[k];
        h1[b * 33 + j] = fmaxf(s, 0.f);
    }
    __syncthreads();
#pragma unroll
    for (int jj = 0; jj < 8; ++jj) {
        int j = q * 8 + jj;
        float s = b2[j];
        const float* wr = w2 + j * 32;
        const float* hr = &h1[b * 33];
#pragma unroll
        for (int k = 0; k < 32; ++k) s += hr[k] * wr[k];
        h2[b * 33 + j] = fmaxf(s, 0.f);
    }
    __syncthreads();
    if (q == 0) {
        float best = -1e30f; int bi = 0;
        const float* hr = &h2[b * 33];
#pragma unroll
        for (int a = 0; a < 5; ++a) {
            float s = b3[a];
            const float* wr = w3 + a * 32;
#pragma unroll
            for (int k = 0; k < 32; ++k) s += hr[k] * wr[k];
            if (s > best) { best = s; bi = a; }   // strict > = first-max, matches jnp.argmax
        }
        pre[b] = bi;
    }
}

// ---------------- LSTM chains ----------------
// 5 blocks, one per class p. Thread j owns row (j&3)*128 + (j>>2) of whh.
__global__ __launch_bounds__(512) void k_lstm(
    const float* __restrict__ cbuf, const int* __restrict__ pre,
    const float* __restrict__ w_ih, const float* __restrict__ w_hh,
    const float* __restrict__ b_ih, const float* __restrict__ b_hh,
    const float* __restrict__ hn0, const float* __restrict__ cn0,
    float* __restrict__ rbuf)
{
    __shared__ float hl[2][128];
    __shared__ float xl[100];
    __shared__ float rl[100];
    int tid = threadIdx.x;
    int p = blockIdx.x;
    int gate = tid & 3, unit = tid >> 2;
    int row = gate * 128 + unit;

    const float* wrow = w_hh + ((size_t)p * 512 + row) * 128;
    float4 wv[32];
#pragma unroll
    for (int k = 0; k < 32; ++k) wv[k] = ((const float4*)wrow)[k];
    float wih_r = w_ih[p * 512 + row];
    float bsum  = b_ih[p * 512 + row] + b_hh[p * 512 + row];
    float gs = (gate == 2) ? 2.f : 1.f;   // tanh for gate g, sigmoid otherwise
    float gc = 1.f - gs;

    float h_u = hn0[p * 128 + unit];      // live only in gate==0 lanes
    float c_u = cn0[p * 128 + unit];

    for (int b = 0; b < 64; ++b) {
        if (pre[b] != p) continue;        // uniform branch
        if (tid < 100) xl[tid] = cbuf[b * 100 + tid];
        if (gate == 0) hl[0][unit] = h_u;
        __syncthreads();
        int par = 0;
        for (int t = 0; t < 100; ++t) {
            float xt = xl[t];
            const float4* hb = (const float4*)hl[par];
            float a0 = 0.f, a1 = 0.f, a2 = 0.f, a3 = 0.f;
#pragma unroll
            for (int k = 0; k < 32; ++k) {
                float4 hv = hb[k];
                a0 += wv[k].x * hv.x; a1 += wv[k].y * hv.y;
                a2 += wv[k].z * hv.z; a3 += wv[k].w * hv.w;
            }
            float gsum = (a0 + a1) + (a2 + a3) + wih_r * xt + bsum;
            float tt  = 1.f / (1.f + expf(-gs * gsum));
            float act = gs * tt + gc;     // sigmoid, or tanh when gate==2
            float v1 = __shfl_xor(act, 1);
            float v2 = __shfl_xor(act, 2);
            float v3 = __shfl_xor(act, 3);
            if (gate == 0) {
                c_u = v1 * c_u + act * v2;            // sig(f)*c + sig(i)*tanh(g)
                float e  = expf(-2.f * c_u);
                float th = 2.f / (1.f + e) - 1.f;     // tanh(c)
                h_u = v3 * th;                        // sig(o)*tanh(c)
                hl[par ^ 1][unit] = h_u;
                if (unit == 127) rl[t] = h_u;
            }
            par ^= 1;
            __syncthreads();
        }
        if (tid < 100) rbuf[b * 100 + tid] = rl[tid];
    }
}

// ---------------- final linear ----------------
__global__ __launch_bounds__(320) void k_stack(
    const float* __restrict__ rbuf, const float* __restrict__ sw,
    const float* __restrict__ sb, float* __restrict__ out)
{
    int i = threadIdx.x;
    if (i >= 320) return;
    int b = i / 5, a = i - b * 5;
    float s = sb[a];
    const float* rr = rbuf + b * 100;
    const float* wr = sw + a * 100;
    for (int k = 0; k < 100; ++k) s += rr[k] * wr[k];
    out[i] = s;
}

extern "C" void kernel_launch(void* const* d_in, const int* in_sizes, int n_in,
                              void* d_out, int out_size, void* d_ws, size_t ws_size,
                              hipStream_t stream) {
    const float* x     = (const float*)d_in[0];
    const float* cw1   = (const float*)d_in[1];
    const float* cb1   = (const float*)d_in[2];
    const float* g1    = (const float*)d_in[3];
    const float* be1   = (const float*)d_in[4];
    const float* m1    = (const float*)d_in[5];
    const float* v1    = (const float*)d_in[6];
    const float* cw2   = (const float*)d_in[7];
    const float* cb2   = (const float*)d_in[8];
    const float* g2    = (const float*)d_in[9];
    const float* be2   = (const float*)d_in[10];
    const float* m2    = (const float*)d_in[11];
    const float* v2    = (const float*)d_in[12];
    const float* pw1   = (const float*)d_in[13];
    const float* pb1   = (const float*)d_in[14];
    const float* pw2   = (const float*)d_in[15];
    const float* pb2   = (const float*)d_in[16];
    const float* pw3   = (const float*)d_in[17];
    const float* pb3   = (const float*)d_in[18];
    const float* wih   = (const float*)d_in[19];
    const float* whh   = (const float*)d_in[20];
    const float* bih   = (const float*)d_in[21];
    const float* bhh   = (const float*)d_in[22];
    const float* hn0   = (const float*)d_in[23];
    const float* cn0   = (const float*)d_in[24];
    const float* sw    = (const float*)d_in[25];
    const float* sb    = (const float*)d_in[26];

    float* y1   = (float*)d_ws;                 // 64*16*60*60 floats
    float* cbuf = y1 + (size_t)64 * 16 * 3600;  // 6400
    float* rbuf = cbuf + 6400;                  // 6400
    int*   pre  = (int*)(rbuf + 6400);          // 64

    dim3 gc1(15, 64);
    k_conv1<<<gc1, 256, 0, stream>>>(x, cw1, cb1, g1, be1, m1, v1, y1);
    k_conv2<<<25, 256, 0, stream>>>(y1, cw2, cb2, g2, be2, m2, v2, cbuf);
    k_mlp<<<1, 256, 0, stream>>>(cbuf, pw1, pb1, pw2, pb2, pw3, pb3, pre);
    k_lstm<<<5, 512, 0, stream>>>(cbuf, pre, wih, whh, bih, bhh, hn0, cn0, rbuf);
    k_stack<<<1, 320, 0, stream>>>(rbuf, sw, sb, (float*)d_out);
}

// Round 3
// 4853.072 us; speedup vs baseline: 1.1421x; 1.1421x over previous
//
#include <hip/hip_runtime.h>
#include <hip/hip_bf16.h>
#include <math.h>

#define EPSF 1e-5f

// DPP quad-perm lane swaps (xor 1/2/3 within each quad), ~2cyc, no LDS pipe.
#define QPERM(x, ctrl) __int_as_float(__builtin_amdgcn_update_dpp( \
    0, __float_as_int(x), (ctrl), 0xF, 0xF, true))
#define QP_XOR1 0xB1   // [1,0,3,2]
#define QP_XOR2 0x4E   // [2,3,0,1]
#define QP_XOR3 0x1B   // [3,2,1,0]

// ---------------- conv1 + bn1 + relu + pool1 ----------------
// x (64,3,480,480) -> y1 (64,16,60,60)
__global__ __launch_bounds__(256) void k_conv1(
    const float* __restrict__ x, const float* __restrict__ w1,
    const float* __restrict__ b1, const float* __restrict__ g1,
    const float* __restrict__ be1, const float* __restrict__ m1,
    const float* __restrict__ v1, float* __restrict__ y1)
{
    __shared__ float wl[768];          // [c][kr][kc][ch]
    __shared__ float al[16], dl[16];
    int tid = threadIdx.x;
    for (int s = tid; s < 768; s += 256) {
        int ch = s / 48; int rem = s - ch * 48;   // rem = c*16 + kr*4 + kc
        wl[rem * 16 + ch] = w1[s];
    }
    if (tid < 16) {
        float a = g1[tid] / sqrtf(v1[tid] + EPSF);
        al[tid] = a;
        dl[tid] = be1[tid] + a * (b1[tid] - m1[tid]);
    }
    __syncthreads();

    int b = blockIdx.y;
    int pix = blockIdx.x * 256 + tid;
    if (pix >= 3600) return;
    int ph = pix / 60, pw = pix - ph * 60;

    float acc[4][16];
#pragma unroll
    for (int i = 0; i < 4; ++i)
#pragma unroll
        for (int ch = 0; ch < 16; ++ch) acc[i][ch] = 0.f;

    const float* xb = x + (size_t)b * 3 * 480 * 480;
#pragma unroll
    for (int c = 0; c < 3; ++c) {
        const float* xc = xb + (size_t)c * 480 * 480;
#pragma unroll
        for (int kr = 0; kr < 4; ++kr) {
            const float* r0 = xc + (size_t)(ph * 8 + kr) * 480 + pw * 8;
            const float* r1 = r0 + 4 * 480;
            float4 A0 = *(const float4*)r0;
            float4 A1 = *(const float4*)(r0 + 4);
            float4 B0 = *(const float4*)r1;
            float4 B1 = *(const float4*)(r1 + 4);
            const float* wbase = &wl[(c * 4 + kr) * 64];
#pragma unroll
            for (int kc = 0; kc < 4; ++kc) {
                float p00 = ((const float*)&A0)[kc];
                float p01 = ((const float*)&A1)[kc];
                float p10 = ((const float*)&B0)[kc];
                float p11 = ((const float*)&B1)[kc];
                const float4* wv4 = (const float4*)(wbase + kc * 16);
#pragma unroll
                for (int q = 0; q < 4; ++q) {
                    float4 w = wv4[q];
                    acc[0][q*4+0] += p00 * w.x; acc[0][q*4+1] += p00 * w.y;
                    acc[0][q*4+2] += p00 * w.z; acc[0][q*4+3] += p00 * w.w;
                    acc[1][q*4+0] += p01 * w.x; acc[1][q*4+1] += p01 * w.y;
                    acc[1][q*4+2] += p01 * w.z; acc[1][q*4+3] += p01 * w.w;
                    acc[2][q*4+0] += p10 * w.x; acc[2][q*4+1] += p10 * w.y;
                    acc[2][q*4+2] += p10 * w.z; acc[2][q*4+3] += p10 * w.w;
                    acc[3][q*4+0] += p11 * w.x; acc[3][q*4+1] += p11 * w.y;
                    acc[3][q*4+2] += p11 * w.z; acc[3][q*4+3] += p11 * w.w;
                }
            }
        }
    }

    float* yb = y1 + (size_t)b * 16 * 3600 + ph * 60 + pw;
#pragma unroll
    for (int ch = 0; ch < 16; ++ch) {
        float a = al[ch], d = dl[ch];
        float v0 = fmaxf(a * acc[0][ch] + d, 0.f);
        float v1x = fmaxf(a * acc[1][ch] + d, 0.f);
        float v2x = fmaxf(a * acc[2][ch] + d, 0.f);
        float v3x = fmaxf(a * acc[3][ch] + d, 0.f);
        yb[(size_t)ch * 3600] = fmaxf(fmaxf(v0, v1x), fmaxf(v2x, v3x));
    }
}

// ---------------- conv2 + bn2 + relu + pool2 ----------------
// y1 (64,16,60,60) -> cbuf (64,100)
__global__ __launch_bounds__(256) void k_conv2(
    const float* __restrict__ y1, const float* __restrict__ w2,
    const float* __restrict__ b2, const float* __restrict__ g2,
    const float* __restrict__ be2, const float* __restrict__ m2,
    const float* __restrict__ v2q, float* __restrict__ cbuf)
{
    __shared__ float wl[144];
    __shared__ float a2s, d2s;
    int tid = threadIdx.x;
    if (tid < 144) wl[tid] = w2[tid];
    if (tid == 0) {
        float a = g2[0] / sqrtf(v2q[0] + EPSF);
        a2s = a;
        d2s = be2[0] + a * (b2[0] - m2[0]);
    }
    __syncthreads();
    int idx = blockIdx.x * 256 + tid;
    if (idx >= 6400) return;
    int b = idx / 100; int i = idx - b * 100;
    int ph = i / 10, pw = i - ph * 10;

    float acc[4] = {0.f, 0.f, 0.f, 0.f};
    const float* yb = y1 + (size_t)b * 16 * 3600;
    for (int c = 0; c < 16; ++c) {
        const float* yc = yb + (size_t)c * 3600;
#pragma unroll
        for (int pr = 0; pr < 2; ++pr)
#pragma unroll
            for (int kr = 0; kr < 3; ++kr) {
                const float* row = yc + (ph * 6 + pr * 3 + kr) * 60 + pw * 6;
                float x0 = row[0], x1 = row[1], x2 = row[2];
                float x3 = row[3], x4 = row[4], x5 = row[5];
                const float* wr = &wl[(c * 3 + kr) * 3];
                float w0 = wr[0], w1v = wr[1], w2v = wr[2];
                acc[pr*2+0] += x0 * w0 + x1 * w1v + x2 * w2v;
                acc[pr*2+1] += x3 * w0 + x4 * w1v + x5 * w2v;
            }
    }
    float a = a2s, d = d2s;
    float q0 = fmaxf(a * acc[0] + d, 0.f);
    float q1 = fmaxf(a * acc[1] + d, 0.f);
    float q2 = fmaxf(a * acc[2] + d, 0.f);
    float q3 = fmaxf(a * acc[3] + d, 0.f);
    cbuf[idx] = fmaxf(fmaxf(q0, q1), fmaxf(q2, q3));
}

// ---------------- MLP + argmax -> pre ----------------
__global__ __launch_bounds__(256) void k_mlp(
    const float* __restrict__ cbuf,
    const float* __restrict__ w1, const float* __restrict__ b1,
    const float* __restrict__ w2, const float* __restrict__ b2,
    const float* __restrict__ w3, const float* __restrict__ b3,
    int* __restrict__ pre)
{
    __shared__ float cl[64 * 101];
    __shared__ float h1[64 * 33];
    __shared__ float h2[64 * 33];
    int tid = threadIdx.x;
    for (int s = tid; s < 6400; s += 256) {
        int bb = s / 100, k = s - bb * 100;
        cl[bb * 101 + k] = cbuf[s];
    }
    __syncthreads();
    int b = tid & 63, q = tid >> 6;     // wave-uniform q
#pragma unroll
    for (int jj = 0; jj < 8; ++jj) {
        int j = q * 8 + jj;
        float s = b1[j];
        const float* wr = w1 + j * 100;
        const float* cr = &cl[b * 101];
        for (int k = 0; k < 100; ++k) s += cr[k] * wr[k];
        h1[b * 33 + j] = fmaxf(s, 0.f);
    }
    __syncthreads();
#pragma unroll
    for (int jj = 0; jj < 8; ++jj) {
        int j = q * 8 + jj;
        float s = b2[j];
        const float* wr = w2 + j * 32;
        const float* hr = &h1[b * 33];
#pragma unroll
        for (int k = 0; k < 32; ++k) s += hr[k] * wr[k];
        h2[b * 33 + j] = fmaxf(s, 0.f);
    }
    __syncthreads();
    if (q == 0) {
        float best = -1e30f; int bi = 0;
        const float* hr = &h2[b * 33];
#pragma unroll
        for (int a = 0; a < 5; ++a) {
            float s = b3[a];
            const float* wr = w3 + a * 32;
#pragma unroll
            for (int k = 0; k < 32; ++k) s += hr[k] * wr[k];
            if (s > best) { best = s; bi = a; }   // strict > = first-max, matches jnp.argmax
        }
        pre[b] = bi;
    }
}

// ---------------- LSTM chains ----------------
// 5 blocks, one per class p. Thread j owns row (j&3)*128 + (j>>2) of whh.
// __launch_bounds__(512,2): 2 waves/SIMD -> 256-VGPR budget so wv[] stays
// register-resident (round-0 VGPR_Count=84 proved it was spilled/reloaded).
__global__ __launch_bounds__(512, 2) void k_lstm(
    const float* __restrict__ cbuf, const int* __restrict__ pre,
    const float* __restrict__ w_ih, const float* __restrict__ w_hh,
    const float* __restrict__ b_ih, const float* __restrict__ b_hh,
    const float* __restrict__ hn0, const float* __restrict__ cn0,
    float* __restrict__ rbuf)
{
    __shared__ float hl[2][128];
    __shared__ float xl[100];
    __shared__ float rl[100];
    int tid = threadIdx.x;
    int p = blockIdx.x;
    int gate = tid & 3, unit = tid >> 2;
    int row = gate * 128 + unit;

    const float* wrow = w_hh + ((size_t)p * 512 + row) * 128;
    float4 wv[32];
#pragma unroll
    for (int k = 0; k < 32; ++k) wv[k] = ((const float4*)wrow)[k];
    float wih_r = w_ih[p * 512 + row];
    float bsum  = b_ih[p * 512 + row] + b_hh[p * 512 + row];
    float gs = (gate == 2) ? 2.f : 1.f;   // tanh for gate g, sigmoid otherwise
    float gc = 1.f - gs;

    float h_u = hn0[p * 128 + unit];      // live only in gate==0 lanes
    float c_u = cn0[p * 128 + unit];

    for (int b = 0; b < 64; ++b) {
        if (pre[b] != p) continue;        // uniform branch
        if (tid < 100) xl[tid] = cbuf[b * 100 + tid];
        if (gate == 0) hl[0][unit] = h_u;
        __syncthreads();
        int par = 0;
        for (int t = 0; t < 100; ++t) {
            float xt = xl[t];
            const float4* hb = (const float4*)hl[par];
            float a0 = 0.f, a1 = 0.f, a2 = 0.f, a3 = 0.f;
#pragma unroll
            for (int k = 0; k < 32; ++k) {
                float4 hv = hb[k];
                a0 += wv[k].x * hv.x; a1 += wv[k].y * hv.y;
                a2 += wv[k].z * hv.z; a3 += wv[k].w * hv.w;
            }
            float gsum = (a0 + a1) + (a2 + a3) + wih_r * xt + bsum;
            // sigmoid (gates i,f,o) or tanh (gate g) via gs/gc trick,
            // fast native exp + rcp (error margin is ~600x the threshold)
            float tt  = __builtin_amdgcn_rcpf(1.f + __expf(-gs * gsum));
            float act = gs * tt + gc;
            float v1 = QPERM(act, QP_XOR1);
            float v2 = QPERM(act, QP_XOR2);
            float v3 = QPERM(act, QP_XOR3);
            if (gate == 0) {
                c_u = v1 * c_u + act * v2;            // sig(f)*c + sig(i)*tanh(g)
                float e  = __expf(-2.f * c_u);
                float th = 2.f * __builtin_amdgcn_rcpf(1.f + e) - 1.f;  // tanh(c)
                h_u = v3 * th;                        // sig(o)*tanh(c)
                hl[par ^ 1][unit] = h_u;
                if (unit == 127) rl[t] = h_u;
            }
            par ^= 1;
            __syncthreads();
        }
        if (tid < 100) rbuf[b * 100 + tid] = rl[tid];
    }
}

// ---------------- final linear ----------------
__global__ __launch_bounds__(320) void k_stack(
    const float* __restrict__ rbuf, const float* __restrict__ sw,
    const float* __restrict__ sb, float* __restrict__ out)
{
    int i = threadIdx.x;
    if (i >= 320) return;
    int b = i / 5, a = i - b * 5;
    float s = sb[a];
    const float* rr = rbuf + b * 100;
    const float* wr = sw + a * 100;
    for (int k = 0; k < 100; ++k) s += rr[k] * wr[k];
    out[i] = s;
}

extern "C" void kernel_launch(void* const* d_in, const int* in_sizes, int n_in,
                              void* d_out, int out_size, void* d_ws, size_t ws_size,
                              hipStream_t stream) {
    const float* x     = (const float*)d_in[0];
    const float* cw1   = (const float*)d_in[1];
    const float* cb1   = (const float*)d_in[2];
    const float* g1    = (const float*)d_in[3];
    const float* be1   = (const float*)d_in[4];
    const float* m1    = (const float*)d_in[5];
    const float* v1    = (const float*)d_in[6];
    const float* cw2   = (const float*)d_in[7];
    const float* cb2   = (const float*)d_in[8];
    const float* g2    = (const float*)d_in[9];
    const float* be2   = (const float*)d_in[10];
    const float* m2    = (const float*)d_in[11];
    const float* v2    = (const float*)d_in[12];
    const float* pw1   = (const float*)d_in[13];
    const float* pb1   = (const float*)d_in[14];
    const float* pw2   = (const float*)d_in[15];
    const float* pb2   = (const float*)d_in[16];
    const float* pw3   = (const float*)d_in[17];
    const float* pb3   = (const float*)d_in[18];
    const float* wih   = (const float*)d_in[19];
    const float* whh   = (const float*)d_in[20];
    const float* bih   = (const float*)d_in[21];
    const float* bhh   = (const float*)d_in[22];
    const float* hn0   = (const float*)d_in[23];
    const float* cn0   = (const float*)d_in[24];
    const float* sw    = (const float*)d_in[25];
    const float* sb    = (const float*)d_in[26];

    float* y1   = (float*)d_ws;                 // 64*16*60*60 floats
    float* cbuf = y1 + (size_t)64 * 16 * 3600;  // 6400
    float* rbuf = cbuf + 6400;                  // 6400
    int*   pre  = (int*)(rbuf + 6400);          // 64

    dim3 gc1(15, 64);
    k_conv1<<<gc1, 256, 0, stream>>>(x, cw1, cb1, g1, be1, m1, v1, y1);
    k_conv2<<<25, 256, 0, stream>>>(y1, cw2, cb2, g2, be2, m2, v2, cbuf);
    k_mlp<<<1, 256, 0, stream>>>(cbuf, pw1, pb1, pw2, pb2, pw3, pb3, pre);
    k_lstm<<<5, 512, 0, stream>>>(cbuf, pre, wih, whh, bih, bhh, hn0, cn0, rbuf);
    k_stack<<<1, 320, 0, stream>>>(rbuf, sw, sb, (float*)d_out);
}

// Round 5
// 4338.156 us; speedup vs baseline: 1.2777x; 1.1187x over previous
//
#include <hip/hip_runtime.h>
#include <hip/hip_bf16.h>
#include <math.h>

#define EPSF 1e-5f

typedef __attribute__((ext_vector_type(2))) float f2;

// DPP quad-perm lane swaps (xor 1/2/3 within each quad), ~2cyc, no LDS pipe.
#define QPERM(x, ctrl) __int_as_float(__builtin_amdgcn_update_dpp( \
    0, __float_as_int(x), (ctrl), 0xF, 0xF, true))
#define QP_XOR1 0xB1   // [1,0,3,2]
#define QP_XOR2 0x4E   // [2,3,0,1]
#define QP_XOR3 0x1B   // [3,2,1,0]

// ---------------- conv1 + bn1 + relu + pool1 ----------------
// x (64,3,480,480) -> y1 (64,16,60,60)
__global__ __launch_bounds__(256) void k_conv1(
    const float* __restrict__ x, const float* __restrict__ w1,
    const float* __restrict__ b1, const float* __restrict__ g1,
    const float* __restrict__ be1, const float* __restrict__ m1,
    const float* __restrict__ v1, float* __restrict__ y1)
{
    __shared__ float wl[768];          // [c][kr][kc][ch]
    __shared__ float al[16], dl[16];
    int tid = threadIdx.x;
    for (int s = tid; s < 768; s += 256) {
        int ch = s / 48; int rem = s - ch * 48;   // rem = c*16 + kr*4 + kc
        wl[rem * 16 + ch] = w1[s];
    }
    if (tid < 16) {
        float a = g1[tid] / sqrtf(v1[tid] + EPSF);
        al[tid] = a;
        dl[tid] = be1[tid] + a * (b1[tid] - m1[tid]);
    }
    __syncthreads();

    int b = blockIdx.y;
    int pix = blockIdx.x * 256 + tid;
    if (pix >= 3600) return;
    int ph = pix / 60, pw = pix - ph * 60;

    float acc[4][16];
#pragma unroll
    for (int i = 0; i < 4; ++i)
#pragma unroll
        for (int ch = 0; ch < 16; ++ch) acc[i][ch] = 0.f;

    const float* xb = x + (size_t)b * 3 * 480 * 480;
#pragma unroll
    for (int c = 0; c < 3; ++c) {
        const float* xc = xb + (size_t)c * 480 * 480;
#pragma unroll
        for (int kr = 0; kr < 4; ++kr) {
            const float* r0 = xc + (size_t)(ph * 8 + kr) * 480 + pw * 8;
            const float* r1 = r0 + 4 * 480;
            float4 A0 = *(const float4*)r0;
            float4 A1 = *(const float4*)(r0 + 4);
            float4 B0 = *(const float4*)r1;
            float4 B1 = *(const float4*)(r1 + 4);
            const float* wbase = &wl[(c * 4 + kr) * 64];
#pragma unroll
            for (int kc = 0; kc < 4; ++kc) {
                float p00 = ((const float*)&A0)[kc];
                float p01 = ((const float*)&A1)[kc];
                float p10 = ((const float*)&B0)[kc];
                float p11 = ((const float*)&B1)[kc];
                const float4* wv4 = (const float4*)(wbase + kc * 16);
#pragma unroll
                for (int q = 0; q < 4; ++q) {
                    float4 w = wv4[q];
                    acc[0][q*4+0] += p00 * w.x; acc[0][q*4+1] += p00 * w.y;
                    acc[0][q*4+2] += p00 * w.z; acc[0][q*4+3] += p00 * w.w;
                    acc[1][q*4+0] += p01 * w.x; acc[1][q*4+1] += p01 * w.y;
                    acc[1][q*4+2] += p01 * w.z; acc[1][q*4+3] += p01 * w.w;
                    acc[2][q*4+0] += p10 * w.x; acc[2][q*4+1] += p10 * w.y;
                    acc[2][q*4+2] += p10 * w.z; acc[2][q*4+3] += p10 * w.w;
                    acc[3][q*4+0] += p11 * w.x; acc[3][q*4+1] += p11 * w.y;
                    acc[3][q*4+2] += p11 * w.z; acc[3][q*4+3] += p11 * w.w;
                }
            }
        }
    }

    float* yb = y1 + (size_t)b * 16 * 3600 + ph * 60 + pw;
#pragma unroll
    for (int ch = 0; ch < 16; ++ch) {
        float a = al[ch], d = dl[ch];
        float v0 = fmaxf(a * acc[0][ch] + d, 0.f);
        float v1x = fmaxf(a * acc[1][ch] + d, 0.f);
        float v2x = fmaxf(a * acc[2][ch] + d, 0.f);
        float v3x = fmaxf(a * acc[3][ch] + d, 0.f);
        yb[(size_t)ch * 3600] = fmaxf(fmaxf(v0, v1x), fmaxf(v2x, v3x));
    }
}

// ---------------- conv2 + bn2 + relu + pool2 ----------------
// y1 (64,16,60,60) -> cbuf (64,100)
__global__ __launch_bounds__(256) void k_conv2(
    const float* __restrict__ y1, const float* __restrict__ w2,
    const float* __restrict__ b2, const float* __restrict__ g2,
    const float* __restrict__ be2, const float* __restrict__ m2,
    const float* __restrict__ v2q, float* __restrict__ cbuf)
{
    __shared__ float wl[144];
    __shared__ float a2s, d2s;
    int tid = threadIdx.x;
    if (tid < 144) wl[tid] = w2[tid];
    if (tid == 0) {
        float a = g2[0] / sqrtf(v2q[0] + EPSF);
        a2s = a;
        d2s = be2[0] + a * (b2[0] - m2[0]);
    }
    __syncthreads();
    int idx = blockIdx.x * 256 + tid;
    if (idx >= 6400) return;
    int b = idx / 100; int i = idx - b * 100;
    int ph = i / 10, pw = i - ph * 10;

    float acc[4] = {0.f, 0.f, 0.f, 0.f};
    const float* yb = y1 + (size_t)b * 16 * 3600;
    for (int c = 0; c < 16; ++c) {
        const float* yc = yb + (size_t)c * 3600;
#pragma unroll
        for (int pr = 0; pr < 2; ++pr)
#pragma unroll
            for (int kr = 0; kr < 3; ++kr) {
                const float* row = yc + (ph * 6 + pr * 3 + kr) * 60 + pw * 6;
                float x0 = row[0], x1 = row[1], x2 = row[2];
                float x3 = row[3], x4 = row[4], x5 = row[5];
                const float* wr = &wl[(c * 3 + kr) * 3];
                float w0 = wr[0], w1v = wr[1], w2v = wr[2];
                acc[pr*2+0] += x0 * w0 + x1 * w1v + x2 * w2v;
                acc[pr*2+1] += x3 * w0 + x4 * w1v + x5 * w2v;
            }
    }
    float a = a2s, d = d2s;
    float q0 = fmaxf(a * acc[0] + d, 0.f);
    float q1 = fmaxf(a * acc[1] + d, 0.f);
    float q2 = fmaxf(a * acc[2] + d, 0.f);
    float q3 = fmaxf(a * acc[3] + d, 0.f);
    cbuf[idx] = fmaxf(fmaxf(q0, q1), fmaxf(q2, q3));
}

// ---------------- MLP + argmax -> pre ----------------
__global__ __launch_bounds__(256) void k_mlp(
    const float* __restrict__ cbuf,
    const float* __restrict__ w1, const float* __restrict__ b1,
    const float* __restrict__ w2, const float* __restrict__ b2,
    const float* __restrict__ w3, const float* __restrict__ b3,
    int* __restrict__ pre)
{
    __shared__ float cl[64 * 101];
    __shared__ float h1[64 * 33];
    __shared__ float h2[64 * 33];
    int tid = threadIdx.x;
    for (int s = tid; s < 6400; s += 256) {
        int bb = s / 100, k = s - bb * 100;
        cl[bb * 101 + k] = cbuf[s];
    }
    __syncthreads();
    int b = tid & 63, q = tid >> 6;     // wave-uniform q
#pragma unroll
    for (int jj = 0; jj < 8; ++jj) {
        int j = q * 8 + jj;
        float s = b1[j];
        const float* wr = w1 + j * 100;
        const float* cr = &cl[b * 101];
        for (int k = 0; k < 100; ++k) s += cr[k] * wr[k];
        h1[b * 33 + j] = fmaxf(s, 0.f);
    }
    __syncthreads();
#pragma unroll
    for (int jj = 0; jj < 8; ++jj) {
        int j = q * 8 + jj;
        float s = b2[j];
        const float* wr = w2 + j * 32;
        const float* hr = &h1[b * 33];
#pragma unroll
        for (int k = 0; k < 32; ++k) s += hr[k] * wr[k];
        h2[b * 33 + j] = fmaxf(s, 0.f);
    }
    __syncthreads();
    if (q == 0) {
        float best = -1e30f; int bi = 0;
        const float* hr = &h2[b * 33];
#pragma unroll
        for (int a = 0; a < 5; ++a) {
            float s = b3[a];
            const float* wr = w3 + a * 32;
#pragma unroll
            for (int k = 0; k < 32; ++k) s += hr[k] * wr[k];
            if (s > best) { best = s; bi = a; }   // strict > = first-max, matches jnp.argmax
        }
        pre[b] = bi;
    }
}

// ---------------- LSTM chains ----------------
// 5 blocks, one per class p. Thread j owns row (j&3)*128 + (j>>2) of whh.
// Weights kept in 32 NAMED float4 registers (round-3: the float4[32] array
// went to scratch despite launch_bounds — VGPR_Count stayed 84).
#define W_LIST(F) F(0) F(1) F(2) F(3) F(4) F(5) F(6) F(7) \
  F(8) F(9) F(10) F(11) F(12) F(13) F(14) F(15) \
  F(16) F(17) F(18) F(19) F(20) F(21) F(22) F(23) \
  F(24) F(25) F(26) F(27) F(28) F(29) F(30) F(31)

__global__ __launch_bounds__(512, 2) void k_lstm(
    const float* __restrict__ cbuf, const int* __restrict__ pre,
    const float* __restrict__ w_ih, const float* __restrict__ w_hh,
    const float* __restrict__ b_ih, const float* __restrict__ b_hh,
    const float* __restrict__ hn0, const float* __restrict__ cn0,
    float* __restrict__ rbuf)
{
    __shared__ alignas(16) float hl[2][128];
    __shared__ float xl[100];
    __shared__ float rl[100];
    int tid = threadIdx.x;
    int p = blockIdx.x;
    int gate = tid & 3, unit = tid >> 2;
    int row = gate * 128 + unit;

    const float4* wr4 = (const float4*)(w_hh + ((size_t)p * 512 + row) * 128);
#define DECLW(i) float4 w##i = wr4[i];
    W_LIST(DECLW)
#undef DECLW

    float wih_r = w_ih[p * 512 + row];
    float bsum  = b_ih[p * 512 + row] + b_hh[p * 512 + row];
    float gs = (gate == 2) ? 2.f : 1.f;   // tanh for gate g, sigmoid otherwise
    float gc = 1.f - gs;

    float h_u = hn0[p * 128 + unit];      // live only in gate==0 lanes
    float c_u = cn0[p * 128 + unit];

    for (int b = 0; b < 64; ++b) {
        if (pre[b] != p) continue;        // uniform branch
        if (tid < 100) xl[tid] = cbuf[b * 100 + tid];
        if (gate == 0) hl[0][unit] = h_u;
        __syncthreads();
        int par = 0;
        for (int t = 0; t < 100; ++t) {
            float xt = xl[t];
            const float4* hb4 = (const float4*)hl[par];
            f2 aA; aA.x = 0.f; aA.y = 0.f;
            f2 aB; aB.x = 0.f; aB.y = 0.f;
            // 128-long dot as 64 v_pk_fma_f32 over 2 chains
#define DOTSTEP(i) { float4 hv = hb4[i]; \
            f2 h01; h01.x = hv.x; h01.y = hv.y; \
            f2 h23; h23.x = hv.z; h23.y = hv.w; \
            f2 wlo; wlo.x = w##i.x; wlo.y = w##i.y; \
            f2 whi; whi.x = w##i.z; whi.y = w##i.w; \
            aA = __builtin_elementwise_fma(wlo, h01, aA); \
            aB = __builtin_elementwise_fma(whi, h23, aB); }
            W_LIST(DOTSTEP)
#undef DOTSTEP
            float gsum = (aA.x + aA.y) + (aB.x + aB.y) + wih_r * xt + bsum;
            // sigmoid (gates i,f,o) or tanh (gate g) via gs/gc trick,
            // fast native exp + rcp (error margin is ~600x the threshold)
            float tt  = __builtin_amdgcn_rcpf(1.f + __expf(-gs * gsum));
            float act = gs * tt + gc;
            float v1 = QPERM(act, QP_XOR1);
            float v2 = QPERM(act, QP_XOR2);
            float v3 = QPERM(act, QP_XOR3);
            if (gate == 0) {
                c_u = v1 * c_u + act * v2;            // sig(f)*c + sig(i)*tanh(g)
                float e  = __expf(-2.f * c_u);
                float th = 2.f * __builtin_amdgcn_rcpf(1.f + e) - 1.f;  // tanh(c)
                h_u = v3 * th;                        // sig(o)*tanh(c)
                hl[par ^ 1][unit] = h_u;
                if (unit == 127) rl[t] = h_u;
            }
            par ^= 1;
            __syncthreads();
        }
        if (tid < 100) rbuf[b * 100 + tid] = rl[tid];
    }
}

// ---------------- final linear ----------------
__global__ __launch_bounds__(320) void k_stack(
    const float* __restrict__ rbuf, const float* __restrict__ sw,
    const float* __restrict__ sb, float* __restrict__ out)
{
    int i = threadIdx.x;
    if (i >= 320) return;
    int b = i / 5, a = i - b * 5;
    float s = sb[a];
    const float* rr = rbuf + b * 100;
    const float* wr = sw + a * 100;
    for (int k = 0; k < 100; ++k) s += rr[k] * wr[k];
    out[i] = s;
}

extern "C" void kernel_launch(void* const* d_in, const int* in_sizes, int n_in,
                              void* d_out, int out_size, void* d_ws, size_t ws_size,
                              hipStream_t stream) {
    const float* x     = (const float*)d_in[0];
    const float* cw1   = (const float*)d_in[1];
    const float* cb1   = (const float*)d_in[2];
    const float* g1    = (const float*)d_in[3];
    const float* be1   = (const float*)d_in[4];
    const float* m1    = (const float*)d_in[5];
    const float* v1    = (const float*)d_in[6];
    const float* cw2   = (const float*)d_in[7];
    const float* cb2   = (const float*)d_in[8];
    const float* g2    = (const float*)d_in[9];
    const float* be2   = (const float*)d_in[10];
    const float* m2    = (const float*)d_in[11];
    const float* v2    = (const float*)d_in[12];
    const float* pw1   = (const float*)d_in[13];
    const float* pb1   = (const float*)d_in[14];
    const float* pw2   = (const float*)d_in[15];
    const float* pb2   = (const float*)d_in[16];
    const float* pw3   = (const float*)d_in[17];
    const float* pb3   = (const float*)d_in[18];
    const float* wih   = (const float*)d_in[19];
    const float* whh   = (const float*)d_in[20];
    const float* bih   = (const float*)d_in[21];
    const float* bhh   = (const float*)d_in[22];
    const float* hn0   = (const float*)d_in[23];
    const float* cn0   = (const float*)d_in[24];
    const float* sw    = (const float*)d_in[25];
    const float* sb    = (const float*)d_in[26];

    float* y1   = (float*)d_ws;                 // 64*16*60*60 floats
    float* cbuf = y1 + (size_t)64 * 16 * 3600;  // 6400
    float* rbuf = cbuf + 6400;                  // 6400
    int*   pre  = (int*)(rbuf + 6400);          // 64

    dim3 gc1(15, 64);
    k_conv1<<<gc1, 256, 0, stream>>>(x, cw1, cb1, g1, be1, m1, v1, y1);
    k_conv2<<<25, 256, 0, stream>>>(y1, cw2, cb2, g2, be2, m2, v2, cbuf);
    k_mlp<<<1, 256, 0, stream>>>(cbuf, pw1, pb1, pw2, pb2, pw3, pb3, pre);
    k_lstm<<<5, 512, 0, stream>>>(cbuf, pre, wih, whh, bih, bhh, hn0, cn0, rbuf);
    k_stack<<<1, 320, 0, stream>>>(rbuf, sw, sb, (float*)d_out);
}